// Round 21
// baseline (100.663 us; speedup 1.0000x reference)
//
#include <hip/hip_runtime.h>
#include <cstdint>
#include <cstddef>

typedef __attribute__((ext_vector_type(8))) short bf16x8;
typedef __attribute__((ext_vector_type(4))) float f32x4;
typedef __attribute__((ext_vector_type(4))) unsigned short ushort4v;
typedef __attribute__((ext_vector_type(2))) unsigned int uint2v;
typedef __attribute__((ext_vector_type(4))) unsigned int uint4v;

#define B_SZ   512
#define D1_IN  40
#define T_DIM  1024
#define D1_OUT 120
#define D2_OUT 64
#define OUT0_SZ (B_SZ * D1_OUT * D2_OUT) // 3932160

// per-bn bitmask of nonzero 32-wide k-steps of W (general sparsity skip)
__device__ unsigned int g_wmask[8];

// ---- helpers ----
__device__ __forceinline__ unsigned short f2bf(float f) {   // RNE
    unsigned int u = __float_as_uint(f);
    u += 0x7FFFu + ((u >> 16) & 1u);
    return (unsigned short)(u >> 16);
}
__device__ __forceinline__ void gld16v(const void* g, void* l) {
    __builtin_amdgcn_global_load_lds(
        (const __attribute__((address_space(1))) unsigned int*)g,
        (__attribute__((address_space(3))) unsigned int*)l, 16, 0, 0);
}

// ---- merged small prep: W2 swizzled re-layout (blocks 0..63), wmask (64..71), w1pad (72) ----
__global__ __launch_bounds__(256) void k_prep_small(const float* __restrict__ W1,
                                                    const float* __restrict__ W,
                                                    const float* __restrict__ W2,
                                                    unsigned short* __restrict__ w2g,
                                                    unsigned short* __restrict__ w1p) {
    int blk = blockIdx.x, tid = threadIdx.x;
    if (blk < 64) {
        __shared__ float tile[32][33];
        int c0 = (blk & 1) * 32, r0 = (blk >> 1) * 32;
        int tx = tid & 31, ty = tid >> 5;
        #pragma unroll
        for (int i = 0; i < 4; i++)
            tile[ty + i * 8][tx] = W2[(size_t)(r0 + ty + i * 8) * D2_OUT + c0 + tx];
        __syncthreads();
        #pragma unroll
        for (int i = 0; i < 4; i++) {
            int s = c0 + ty + i * 8;      // 0..63
            int t = r0 + tx;              // 0..1023
            size_t idx = ((size_t)(t >> 6) * 64 + s) * 64
                       + ((((t >> 3) & 7) ^ (s & 7)) << 3) + (t & 7);
            w2g[idx] = f2bf(tile[tx][ty + i * 8]);
        }
    } else if (blk < 72) {
        __shared__ unsigned int sm[256];
        int bn = blk - 64;
        int rbase = tid >> 5, c0 = (tid & 31) * 4;
        unsigned int m = 0;
        for (int ks = 0; ks < 32; ks++) {
            bool nz = false;
            #pragma unroll
            for (int i = 0; i < 4; i++) {
                int r = ks * 32 + rbase + i * 8;
                float4 v = *(const float4*)(W + (size_t)r * T_DIM + bn * 128 + c0);
                nz |= (v.x != 0.f) | (v.y != 0.f) | (v.z != 0.f) | (v.w != 0.f);
            }
            if (nz) m |= (1u << ks);
        }
        sm[tid] = m;
        __syncthreads();
        if (tid == 0) {
            unsigned int acc = 0;
            for (int i = 0; i < 256; i++) acc |= sm[i];
            g_wmask[bn] = acc;
        }
    } else {
        for (int i = tid; i < 128 * 64; i += 256) {
            int o = i >> 6, f = i & 63;
            w1p[i] = (o < D1_OUT && f < D1_IN) ? f2bf(W1[o * D1_IN + f]) : (unsigned short)0;
        }
    }
}

// ---- wfrag: W (1024x1024 fp32) -> MFMA-A-fragment-ordered bf16 ----
__global__ __launch_bounds__(256) void k_wfrag(const float* __restrict__ W,
                                               unsigned short* __restrict__ wfrag) {
    __shared__ float tl[32 * 132];
    int bn = blockIdx.x >> 5, ks = blockIdx.x & 31;
    int tid = threadIdx.x;
    int k0 = ks * 32, c0 = bn * 128;
    for (int i = tid; i < 1024; i += 256) {
        int r = i >> 5, c4 = i & 31;
        float4 v = *(const float4*)(W + (size_t)(k0 + r) * T_DIM + c0 + c4 * 4);
        *(float4*)&tl[r * 132 + c4 * 4] = v;
    }
    __syncthreads();
    int l = tid & 63, v = tid >> 6;      // 4 waves
    int rr = l & 15, q = l >> 4;
    #pragma unroll
    for (int nn = 0; nn < 2; nn++) {
        int n = v + nn * 4;
        bf16x8 o;
        #pragma unroll
        for (int j = 0; j < 8; j++)
            o[j] = (short)f2bf(tl[(q * 8 + j) * 132 + n * 16 + rr]);
        *(bf16x8*)(wfrag + (((size_t)(bn * 32 + ks) * 8 + n) * 512) + (size_t)l * 8) = o;
    }
}

// ---- MEGA: per-b block. Phase 1/2: E = x@W (masked), softmax -> A (output only).
//      Phase 3: fused MFMA1/gate/GEMM2; gate staged straight from A (same-block
//      L2-hot fp32, no side-buffer round-trip); xbt octet-XOR-swizzled. ----
__global__ __launch_bounds__(512) void k_mega(const float* __restrict__ x,
                                              const unsigned short* __restrict__ wfrag,
                                              const unsigned short* __restrict__ w1p,
                                              const unsigned short* __restrict__ w2g,
                                              const float* __restrict__ Bias,
                                              const float* __restrict__ lamp,
                                              float* __restrict__ A,
                                              float* __restrict__ out) {
    __shared__ float xfst[2][10 * 260];           // x chunk fp32, group-padded  20800B
    __shared__ float gst[2][10 * 260];            // A chunk fp32, group-padded  20800B
    __shared__ unsigned short w2s[64 * 64];       // swizzled w2 chunk            8192B
    __shared__ unsigned short xbt[64 * 72];       // x [t][f] octet-swizzled      9216B
    __shared__ unsigned short xtl[128 * 72];      // X_tilde [o][t]              18432B
    __shared__ float red[32][9];                  //                              1152B
    int b = blockIdx.x;
    int tid = threadIdx.x, l = tid & 63, w = tid >> 6;   // 8 waves
    int rr = l & 15, q = l >> 4;
    float lam = fminf(fmaxf(lamp[0], 0.f), 1.f), oml = 1.f - lam;
    unsigned int mask = g_wmask[w];

    // ================= PHASE 1/2 =================
    auto MKFRAG = [&](const float* xrow, int off, bf16x8& o) {
        f32x4 a0 = *(const f32x4*)(xrow + off);
        f32x4 b0 = *(const f32x4*)(xrow + off + 4);
        ((unsigned int*)&o)[0] = (__float_as_uint(a0.x) >> 16) | (__float_as_uint(a0.y) & 0xFFFF0000u);
        ((unsigned int*)&o)[1] = (__float_as_uint(a0.z) >> 16) | (__float_as_uint(a0.w) & 0xFFFF0000u);
        ((unsigned int*)&o)[2] = (__float_as_uint(b0.x) >> 16) | (__float_as_uint(b0.y) & 0xFFFF0000u);
        ((unsigned int*)&o)[3] = (__float_as_uint(b0.z) >> 16) | (__float_as_uint(b0.w) & 0xFFFF0000u);
    };

    {
        // ---- group A: rows b*40 + {0..31} (2 m-tiles) ----
        const float* xrow0 = x + (size_t)(b * 40 + rr) * T_DIM;
        const float* xrow1 = x + (size_t)(b * 40 + 16 + rr) * T_DIM;
        f32x4 acc[2][8] = {};
        for (int ks = 0; ks < 32; ks++) {
            if (!((mask >> ks) & 1u)) continue;
            int off = ks * 32 + q * 8;
            bf16x8 bx0, bx1;
            MKFRAG(xrow0, off, bx0);
            MKFRAG(xrow1, off, bx1);
            const unsigned short* wp = wfrag + ((size_t)(w * 32 + ks) * 8) * 512 + (size_t)l * 8;
            #pragma unroll
            for (int n = 0; n < 8; n++) {
                bf16x8 af = *(const bf16x8*)(wp + (size_t)n * 512);
                acc[0][n] = __builtin_amdgcn_mfma_f32_16x16x32_bf16(af, bx0, acc[0][n], 0, 0, 0);
                acc[1][n] = __builtin_amdgcn_mfma_f32_16x16x32_bf16(af, bx1, acc[1][n], 0, 0, 0);
            }
        }
        #pragma unroll
        for (int m = 0; m < 2; m++) {
            float mx = -3.4e38f;
            #pragma unroll
            for (int n = 0; n < 8; n++)
                #pragma unroll
                for (int jj = 0; jj < 4; jj++) mx = fmaxf(mx, acc[m][n][jj]);
            mx = fmaxf(mx, __shfl_xor(mx, 16));
            mx = fmaxf(mx, __shfl_xor(mx, 32));
            if (l < 16) red[m * 16 + rr][w] = mx;
        }
        __syncthreads();
        float gm[2];
        #pragma unroll
        for (int m = 0; m < 2; m++) {
            float g = red[m * 16 + rr][0];
            #pragma unroll
            for (int ww = 1; ww < 8; ww++) g = fmaxf(g, red[m * 16 + rr][ww]);
            gm[m] = g;
        }
        __syncthreads();
        #pragma unroll
        for (int m = 0; m < 2; m++) {
            float s = 0.f;
            #pragma unroll
            for (int n = 0; n < 8; n++)
                #pragma unroll
                for (int jj = 0; jj < 4; jj++) {
                    float p = __expf(acc[m][n][jj] - gm[m]);
                    acc[m][n][jj] = p;
                    s += p;
                }
            s += __shfl_xor(s, 16);
            s += __shfl_xor(s, 32);
            if (l < 16) red[m * 16 + rr][w] = s;
        }
        __syncthreads();
        #pragma unroll
        for (int m = 0; m < 2; m++) {
            float tot = 0.f;
            #pragma unroll
            for (int ww = 0; ww < 8; ww++) tot += red[m * 16 + rr][ww];
            float inv = 1.f / tot;
            int f = m * 16 + rr;                       // 0..31
            size_t rowg = (size_t)(b * 40 + f) * T_DIM + w * 128;
            #pragma unroll
            for (int n = 0; n < 8; n++) {
                f32x4 o;
                o.x = acc[m][n][0] * inv; o.y = acc[m][n][1] * inv;
                o.z = acc[m][n][2] * inv; o.w = acc[m][n][3] * inv;
                *(f32x4*)&A[rowg + n * 16 + q * 4] = o;
            }
        }
        __syncthreads();                               // red reuse fence
    }
    {
        // ---- group B: rows b*40 + {32..39} (1 m-tile, rr<8 valid) ----
        int rowa = b * 40 + 32 + rr;
        int rowc = rowa < 20480 ? rowa : 20479;        // clamp (b=511, rr>=8)
        const float* xrowB = x + (size_t)rowc * T_DIM;
        f32x4 acc[8] = {};
        for (int ks = 0; ks < 32; ks++) {
            if (!((mask >> ks) & 1u)) continue;
            int off = ks * 32 + q * 8;
            bf16x8 bxB;
            MKFRAG(xrowB, off, bxB);
            const unsigned short* wp = wfrag + ((size_t)(w * 32 + ks) * 8) * 512 + (size_t)l * 8;
            #pragma unroll
            for (int n = 0; n < 8; n++) {
                bf16x8 af = *(const bf16x8*)(wp + (size_t)n * 512);
                acc[n] = __builtin_amdgcn_mfma_f32_16x16x32_bf16(af, bxB, acc[n], 0, 0, 0);
            }
        }
        float mx = -3.4e38f;
        #pragma unroll
        for (int n = 0; n < 8; n++)
            #pragma unroll
            for (int jj = 0; jj < 4; jj++) mx = fmaxf(mx, acc[n][jj]);
        mx = fmaxf(mx, __shfl_xor(mx, 16));
        mx = fmaxf(mx, __shfl_xor(mx, 32));
        if (l < 16) red[rr][w] = mx;
        __syncthreads();
        float g = red[rr][0];
        #pragma unroll
        for (int ww = 1; ww < 8; ww++) g = fmaxf(g, red[rr][ww]);
        __syncthreads();
        float s = 0.f;
        #pragma unroll
        for (int n = 0; n < 8; n++)
            #pragma unroll
            for (int jj = 0; jj < 4; jj++) {
                float p = __expf(acc[n][jj] - g);
                acc[n][jj] = p;
                s += p;
            }
        s += __shfl_xor(s, 16);
        s += __shfl_xor(s, 32);
        if (l < 16) red[rr][w] = s;
        __syncthreads();
        if (rr < 8) {
            float tot = 0.f;
            #pragma unroll
            for (int ww = 0; ww < 8; ww++) tot += red[rr][ww];
            float inv = 1.f / tot;
            int f = 32 + rr;
            size_t rowg = (size_t)(b * 40 + f) * T_DIM + w * 128;
            #pragma unroll
            for (int n = 0; n < 8; n++) {
                f32x4 o;
                o.x = acc[n][0] * inv; o.y = acc[n][1] * inv;
                o.z = acc[n][2] * inv; o.w = acc[n][3] * inv;
                *(f32x4*)&A[rowg + n * 16 + q * 4] = o;
            }
        }
    }
    __syncthreads();   // all A stores drained before phase 3 re-reads A

    // ================= PHASE 3 (fused) =================
    bf16x8 aw[2];
    #pragma unroll
    for (int ks = 0; ks < 2; ks++)
        aw[ks] = *(const bf16x8*)(w1p + (w * 16 + rr) * 64 + ks * 32 + q * 8);
    int og = w * 16 + rr;              // lane's fixed o (strip row)
    int am = og % D1_IN;               // gate row
    int amg = (am >> 2) * 260 + (am & 3) * 64;    // group-padded base of gate row
    f32x4 acc2[4] = {};
    const float* xb = x + (size_t)b * D1_IN * T_DIM;
    const float* Ab = A + (size_t)b * D1_IN * T_DIM;

    auto STAGE_XG = [&](int buf, int tc) {
        int t0 = tc * 64;
        int f = w * 4 + (l >> 4);                 // group w: rows 4w..4w+3
        gld16v(xb + (size_t)f * T_DIM + t0 + (l & 15) * 4, &xfst[buf][w * 260]);
        gld16v(Ab + (size_t)f * T_DIM + t0 + (l & 15) * 4, &gst[buf][w * 260]);
        if (w < 2) {
            int f2 = 32 + w * 4 + (l >> 4);       // groups 8,9: rows 32..39
            gld16v(xb + (size_t)f2 * T_DIM + t0 + (l & 15) * 4, &xfst[buf][(8 + w) * 260]);
            gld16v(Ab + (size_t)f2 * T_DIM + t0 + (l & 15) * 4, &gst[buf][(8 + w) * 260]);
        }
    };
    auto STAGE_W2 = [&](int tc) {
        gld16v(w2g + (size_t)tc * 4096 + w * 512 + l * 8, &w2s[w * 512]);
    };
    // CONVERT: one thread per (octet, t): 8 stride-64 word reads (2-way broadcast,
    // free) -> one b128 write at octet-XOR-swizzled slot (b128 bank floor).
    auto CONVERT = [&](int buf) {
        if (tid < 320) {
            int oct = tid >> 6, tt = tid & 63;
            const float* base = &xfst[buf][0];
            float v[8];
            #pragma unroll
            for (int i = 0; i < 8; i++) {
                int f = oct * 8 + i;
                v[i] = base[(f >> 2) * 260 + (f & 3) * 64 + tt];
            }
            uint4v pk;
            #pragma unroll
            for (int i = 0; i < 4; i++)
                pk[i] = (__float_as_uint(v[2 * i]) >> 16) | (__float_as_uint(v[2 * i + 1]) & 0xFFFF0000u);
            *(uint4v*)&xbt[tt * 72 + ((oct ^ ((tt >> 3) & 7)) << 3)] = pk;
        }
    };

    // zero ALL of xbt once: pad octets (swizzled slots never written) stay zero
    for (int i = tid; i < 2304; i += 512) ((unsigned int*)xbt)[i] = 0u;
    STAGE_XG(0, 0);
    __syncthreads();
    for (int tc = 0; tc < 16; tc++) {
        int cur = tc & 1;
        CONVERT(cur);
        STAGE_W2(tc);
        __syncthreads();                       // A: xbt + gst + w2s ready
        if (tc < 15) STAGE_XG(cur ^ 1, tc + 1);  // prefetch overlaps compute
        // X_bar^T via MFMA: frag read uses the same octet-XOR swizzle
        f32x4 acc1[4] = {};
        #pragma unroll
        for (int ni = 0; ni < 4; ni++) {
            int t = ni * 16 + rr;
            int sw = (t >> 3) & 7;
            #pragma unroll
            for (int ks = 0; ks < 2; ks++) {
                int oct = ks * 4 + q;
                bf16x8 bx = *(const bf16x8*)&xbt[t * 72 + ((oct ^ sw) << 3)];
                acc1[ni] = __builtin_amdgcn_mfma_f32_16x16x32_bf16(bx, aw[ks], acc1[ni], 0, 0, 0);
            }
        }
        // gate (fp32 LDS, lane-fixed row am) + pack -> one ds_write_b64 per ni
        const float* gr = &gst[cur][amg];
        #pragma unroll
        for (int ni = 0; ni < 4; ni++) {
            f32x4 gv = *(const f32x4*)(gr + ni * 16 + q * 4);
            float e0 = acc1[ni][0] * (lam * gv.x + oml);
            float e1 = acc1[ni][1] * (lam * gv.y + oml);
            float e2 = acc1[ni][2] * (lam * gv.z + oml);
            float e3 = acc1[ni][3] * (lam * gv.w + oml);
            uint2 pk;
            pk.x = (unsigned int)f2bf(e0) | ((unsigned int)f2bf(e1) << 16);
            pk.y = (unsigned int)f2bf(e2) | ((unsigned int)f2bf(e3) << 16);
            *(uint2*)&xtl[og * 72 + ni * 16 + q * 4] = pk;
        }
        // GEMM2: a2 row = og (same-wave RAW on xtl), b2 from swizzled w2s LDS
        #pragma unroll
        for (int ks2 = 0; ks2 < 2; ks2++) {
            bf16x8 a2 = *(const bf16x8*)&xtl[og * 72 + ks2 * 32 + q * 8];
            #pragma unroll
            for (int ni = 0; ni < 4; ni++) {
                int s = ni * 16 + rr;
                bf16x8 b2 = *(const bf16x8*)&w2s[s * 64 + (((ks2 * 4 + q) ^ (s & 7)) << 3)];
                acc2[ni] = __builtin_amdgcn_mfma_f32_16x16x32_bf16(a2, b2, acc2[ni], 0, 0, 0);
            }
        }
        __syncthreads();                       // B: drains prefetch; protects buffers
    }
    #pragma unroll
    for (int ni = 0; ni < 4; ni++)
        #pragma unroll
        for (int j = 0; j < 4; j++) {
            int row = w * 16 + q * 4 + j;
            if (row < D1_OUT) {
                int col = ni * 16 + rr;
                float v = acc2[ni][j] + Bias[row * D2_OUT + col];
                out[((size_t)b * D1_OUT + row) * D2_OUT + col] = fmaxf(v, 0.f);
            }
        }
}

extern "C" void kernel_launch(void* const* d_in, const int* in_sizes, int n_in,
                              void* d_out, int out_size, void* d_ws, size_t ws_size,
                              hipStream_t stream) {
    const float* x    = (const float*)d_in[0];
    const float* W1   = (const float*)d_in[1];
    const float* W    = (const float*)d_in[2];
    const float* W2   = (const float*)d_in[3];
    const float* Bias = (const float*)d_in[4];
    const float* lam  = (const float*)d_in[5];
    float* out = (float*)d_out;
    float* A   = out + OUT0_SZ;                    // second output region

    char* ws = (char*)d_ws;
    unsigned short* wfrag = (unsigned short*)(ws);              // 2 MB
    unsigned short* w2g   = (unsigned short*)(ws + 2097152);    // 128 KB
    unsigned short* w1p   = (unsigned short*)(ws + 2228224);    // 16 KB (total ~2.25 MB)

    hipLaunchKernelGGL(k_prep_small, dim3(73), dim3(256), 0, stream, W1, W, W2, w2g, w1p);
    hipLaunchKernelGGL(k_wfrag, dim3(256), dim3(256), 0, stream, W, wfrag);
    hipLaunchKernelGGL(k_mega, dim3(512), dim3(512), 0, stream, x, wfrag, w1p, w2g, Bias, lam, A, out);
}

// Round 22
// 94.804 us; speedup vs baseline: 1.0618x; 1.0618x over previous
//
#include <hip/hip_runtime.h>
#include <cstdint>
#include <cstddef>

typedef __attribute__((ext_vector_type(8))) short bf16x8;
typedef __attribute__((ext_vector_type(4))) float f32x4;
typedef __attribute__((ext_vector_type(4))) unsigned short ushort4v;
typedef __attribute__((ext_vector_type(2))) unsigned int uint2v;
typedef __attribute__((ext_vector_type(4))) unsigned int uint4v;

#define B_SZ   512
#define D1_IN  40
#define T_DIM  1024
#define D1_OUT 120
#define D2_OUT 64
#define OUT0_SZ (B_SZ * D1_OUT * D2_OUT) // 3932160
#define GSTR   264   // group stride (words) for xfst/gst: 264 % 32 == 8 -> conflict-free

// per-bn bitmask of nonzero 32-wide k-steps of W (general sparsity skip)
__device__ unsigned int g_wmask[8];

// ---- helpers ----
__device__ __forceinline__ unsigned short f2bf(float f) {   // RNE
    unsigned int u = __float_as_uint(f);
    u += 0x7FFFu + ((u >> 16) & 1u);
    return (unsigned short)(u >> 16);
}
__device__ __forceinline__ void gld16v(const void* g, void* l) {
    __builtin_amdgcn_global_load_lds(
        (const __attribute__((address_space(1))) unsigned int*)g,
        (__attribute__((address_space(3))) unsigned int*)l, 16, 0, 0);
}

// ---- merged small prep: W2 swizzled re-layout (blocks 0..63), wmask (64..71), w1pad (72) ----
__global__ __launch_bounds__(256) void k_prep_small(const float* __restrict__ W1,
                                                    const float* __restrict__ W,
                                                    const float* __restrict__ W2,
                                                    unsigned short* __restrict__ w2g,
                                                    unsigned short* __restrict__ w1p) {
    int blk = blockIdx.x, tid = threadIdx.x;
    if (blk < 64) {
        __shared__ float tile[32][33];
        int c0 = (blk & 1) * 32, r0 = (blk >> 1) * 32;
        int tx = tid & 31, ty = tid >> 5;
        #pragma unroll
        for (int i = 0; i < 4; i++)
            tile[ty + i * 8][tx] = W2[(size_t)(r0 + ty + i * 8) * D2_OUT + c0 + tx];
        __syncthreads();
        #pragma unroll
        for (int i = 0; i < 4; i++) {
            int s = c0 + ty + i * 8;      // 0..63
            int t = r0 + tx;              // 0..1023
            size_t idx = ((size_t)(t >> 6) * 64 + s) * 64
                       + ((((t >> 3) & 7) ^ (s & 7)) << 3) + (t & 7);
            w2g[idx] = f2bf(tile[tx][ty + i * 8]);
        }
    } else if (blk < 72) {
        __shared__ unsigned int sm[256];
        int bn = blk - 64;
        int rbase = tid >> 5, c0 = (tid & 31) * 4;
        unsigned int m = 0;
        for (int ks = 0; ks < 32; ks++) {
            bool nz = false;
            #pragma unroll
            for (int i = 0; i < 4; i++) {
                int r = ks * 32 + rbase + i * 8;
                float4 v = *(const float4*)(W + (size_t)r * T_DIM + bn * 128 + c0);
                nz |= (v.x != 0.f) | (v.y != 0.f) | (v.z != 0.f) | (v.w != 0.f);
            }
            if (nz) m |= (1u << ks);
        }
        sm[tid] = m;
        __syncthreads();
        if (tid == 0) {
            unsigned int acc = 0;
            for (int i = 0; i < 256; i++) acc |= sm[i];
            g_wmask[bn] = acc;
        }
    } else {
        for (int i = tid; i < 128 * 64; i += 256) {
            int o = i >> 6, f = i & 63;
            w1p[i] = (o < D1_OUT && f < D1_IN) ? f2bf(W1[o * D1_IN + f]) : (unsigned short)0;
        }
    }
}

// ---- wfrag: W (1024x1024 fp32) -> MFMA-A-fragment-ordered bf16 ----
__global__ __launch_bounds__(256) void k_wfrag(const float* __restrict__ W,
                                               unsigned short* __restrict__ wfrag) {
    __shared__ float tl[32 * 132];
    int bn = blockIdx.x >> 5, ks = blockIdx.x & 31;
    int tid = threadIdx.x;
    int k0 = ks * 32, c0 = bn * 128;
    for (int i = tid; i < 1024; i += 256) {
        int r = i >> 5, c4 = i & 31;
        float4 v = *(const float4*)(W + (size_t)(k0 + r) * T_DIM + c0 + c4 * 4);
        *(float4*)&tl[r * 132 + c4 * 4] = v;
    }
    __syncthreads();
    int l = tid & 63, v = tid >> 6;      // 4 waves
    int rr = l & 15, q = l >> 4;
    #pragma unroll
    for (int nn = 0; nn < 2; nn++) {
        int n = v + nn * 4;
        bf16x8 o;
        #pragma unroll
        for (int j = 0; j < 8; j++)
            o[j] = (short)f2bf(tl[(q * 8 + j) * 132 + n * 16 + rr]);
        *(bf16x8*)(wfrag + (((size_t)(bn * 32 + ks) * 8 + n) * 512) + (size_t)l * 8) = o;
    }
}

// ---- MEGA: per-b block. Phase 1/2: E = x@W (masked), softmax -> A (output only).
//      Phase 3: fused MFMA1/gate/GEMM2; gate staged from A (L2-hot fp32);
//      xbt octet-XOR-swizzled; xfst/gst group stride 264 (conflict-free). ----
__global__ __launch_bounds__(512) void k_mega(const float* __restrict__ x,
                                              const unsigned short* __restrict__ wfrag,
                                              const unsigned short* __restrict__ w1p,
                                              const unsigned short* __restrict__ w2g,
                                              const float* __restrict__ Bias,
                                              const float* __restrict__ lamp,
                                              float* __restrict__ A,
                                              float* __restrict__ out) {
    __shared__ float xfst[2][10 * GSTR];          // x chunk fp32, group-padded  21120B
    __shared__ float gst[2][10 * GSTR];           // A chunk fp32, group-padded  21120B
    __shared__ unsigned short w2s[64 * 64];       // swizzled w2 chunk            8192B
    __shared__ unsigned short xbt[64 * 72];       // x [t][f] octet-swizzled      9216B
    __shared__ unsigned short xtl[128 * 72];      // X_tilde [o][t]              18432B
    __shared__ float red[32][9];                  //                              1152B
    int b = blockIdx.x;
    int tid = threadIdx.x, l = tid & 63, w = tid >> 6;   // 8 waves
    int rr = l & 15, q = l >> 4;
    float lam = fminf(fmaxf(lamp[0], 0.f), 1.f), oml = 1.f - lam;
    unsigned int mask = g_wmask[w];

    // ================= PHASE 1/2 =================
    auto MKFRAG = [&](const float* xrow, int off, bf16x8& o) {
        f32x4 a0 = *(const f32x4*)(xrow + off);
        f32x4 b0 = *(const f32x4*)(xrow + off + 4);
        ((unsigned int*)&o)[0] = (__float_as_uint(a0.x) >> 16) | (__float_as_uint(a0.y) & 0xFFFF0000u);
        ((unsigned int*)&o)[1] = (__float_as_uint(a0.z) >> 16) | (__float_as_uint(a0.w) & 0xFFFF0000u);
        ((unsigned int*)&o)[2] = (__float_as_uint(b0.x) >> 16) | (__float_as_uint(b0.y) & 0xFFFF0000u);
        ((unsigned int*)&o)[3] = (__float_as_uint(b0.z) >> 16) | (__float_as_uint(b0.w) & 0xFFFF0000u);
    };

    {
        // ---- group A: rows b*40 + {0..31} (2 m-tiles) ----
        const float* xrow0 = x + (size_t)(b * 40 + rr) * T_DIM;
        const float* xrow1 = x + (size_t)(b * 40 + 16 + rr) * T_DIM;
        f32x4 acc[2][8] = {};
        for (int ks = 0; ks < 32; ks++) {
            if (!((mask >> ks) & 1u)) continue;
            int off = ks * 32 + q * 8;
            bf16x8 bx0, bx1;
            MKFRAG(xrow0, off, bx0);
            MKFRAG(xrow1, off, bx1);
            const unsigned short* wp = wfrag + ((size_t)(w * 32 + ks) * 8) * 512 + (size_t)l * 8;
            #pragma unroll
            for (int n = 0; n < 8; n++) {
                bf16x8 af = *(const bf16x8*)(wp + (size_t)n * 512);
                acc[0][n] = __builtin_amdgcn_mfma_f32_16x16x32_bf16(af, bx0, acc[0][n], 0, 0, 0);
                acc[1][n] = __builtin_amdgcn_mfma_f32_16x16x32_bf16(af, bx1, acc[1][n], 0, 0, 0);
            }
        }
        #pragma unroll
        for (int m = 0; m < 2; m++) {
            float mx = -3.4e38f;
            #pragma unroll
            for (int n = 0; n < 8; n++)
                #pragma unroll
                for (int jj = 0; jj < 4; jj++) mx = fmaxf(mx, acc[m][n][jj]);
            mx = fmaxf(mx, __shfl_xor(mx, 16));
            mx = fmaxf(mx, __shfl_xor(mx, 32));
            if (l < 16) red[m * 16 + rr][w] = mx;
        }
        __syncthreads();
        float gm[2];
        #pragma unroll
        for (int m = 0; m < 2; m++) {
            float g = red[m * 16 + rr][0];
            #pragma unroll
            for (int ww = 1; ww < 8; ww++) g = fmaxf(g, red[m * 16 + rr][ww]);
            gm[m] = g;
        }
        __syncthreads();
        #pragma unroll
        for (int m = 0; m < 2; m++) {
            float s = 0.f;
            #pragma unroll
            for (int n = 0; n < 8; n++)
                #pragma unroll
                for (int jj = 0; jj < 4; jj++) {
                    float p = __expf(acc[m][n][jj] - gm[m]);
                    acc[m][n][jj] = p;
                    s += p;
                }
            s += __shfl_xor(s, 16);
            s += __shfl_xor(s, 32);
            if (l < 16) red[m * 16 + rr][w] = s;
        }
        __syncthreads();
        #pragma unroll
        for (int m = 0; m < 2; m++) {
            float tot = 0.f;
            #pragma unroll
            for (int ww = 0; ww < 8; ww++) tot += red[m * 16 + rr][ww];
            float inv = 1.f / tot;
            int f = m * 16 + rr;                       // 0..31
            size_t rowg = (size_t)(b * 40 + f) * T_DIM + w * 128;
            #pragma unroll
            for (int n = 0; n < 8; n++) {
                f32x4 o;
                o.x = acc[m][n][0] * inv; o.y = acc[m][n][1] * inv;
                o.z = acc[m][n][2] * inv; o.w = acc[m][n][3] * inv;
                *(f32x4*)&A[rowg + n * 16 + q * 4] = o;
            }
        }
        __syncthreads();                               // red reuse fence
    }
    {
        // ---- group B: rows b*40 + {32..39} (1 m-tile, rr<8 valid) ----
        int rowa = b * 40 + 32 + rr;
        int rowc = rowa < 20480 ? rowa : 20479;        // clamp (b=511, rr>=8)
        const float* xrowB = x + (size_t)rowc * T_DIM;
        f32x4 acc[8] = {};
        for (int ks = 0; ks < 32; ks++) {
            if (!((mask >> ks) & 1u)) continue;
            int off = ks * 32 + q * 8;
            bf16x8 bxB;
            MKFRAG(xrowB, off, bxB);
            const unsigned short* wp = wfrag + ((size_t)(w * 32 + ks) * 8) * 512 + (size_t)l * 8;
            #pragma unroll
            for (int n = 0; n < 8; n++) {
                bf16x8 af = *(const bf16x8*)(wp + (size_t)n * 512);
                acc[n] = __builtin_amdgcn_mfma_f32_16x16x32_bf16(af, bxB, acc[n], 0, 0, 0);
            }
        }
        float mx = -3.4e38f;
        #pragma unroll
        for (int n = 0; n < 8; n++)
            #pragma unroll
            for (int jj = 0; jj < 4; jj++) mx = fmaxf(mx, acc[n][jj]);
        mx = fmaxf(mx, __shfl_xor(mx, 16));
        mx = fmaxf(mx, __shfl_xor(mx, 32));
        if (l < 16) red[rr][w] = mx;
        __syncthreads();
        float g = red[rr][0];
        #pragma unroll
        for (int ww = 1; ww < 8; ww++) g = fmaxf(g, red[rr][ww]);
        __syncthreads();
        float s = 0.f;
        #pragma unroll
        for (int n = 0; n < 8; n++)
            #pragma unroll
            for (int jj = 0; jj < 4; jj++) {
                float p = __expf(acc[n][jj] - g);
                acc[n][jj] = p;
                s += p;
            }
        s += __shfl_xor(s, 16);
        s += __shfl_xor(s, 32);
        if (l < 16) red[rr][w] = s;
        __syncthreads();
        if (rr < 8) {
            float tot = 0.f;
            #pragma unroll
            for (int ww = 0; ww < 8; ww++) tot += red[rr][ww];
            float inv = 1.f / tot;
            int f = 32 + rr;
            size_t rowg = (size_t)(b * 40 + f) * T_DIM + w * 128;
            #pragma unroll
            for (int n = 0; n < 8; n++) {
                f32x4 o;
                o.x = acc[n][0] * inv; o.y = acc[n][1] * inv;
                o.z = acc[n][2] * inv; o.w = acc[n][3] * inv;
                *(f32x4*)&A[rowg + n * 16 + q * 4] = o;
            }
        }
    }
    __syncthreads();   // all A stores drained before phase 3 re-reads A

    // ================= PHASE 3 (fused) =================
    bf16x8 aw[2];
    #pragma unroll
    for (int ks = 0; ks < 2; ks++)
        aw[ks] = *(const bf16x8*)(w1p + (w * 16 + rr) * 64 + ks * 32 + q * 8);
    int og = w * 16 + rr;              // lane's fixed o (strip row)
    int am = og % D1_IN;               // gate row
    int amg = (am >> 2) * GSTR + (am & 3) * 64;   // group-padded base of gate row
    f32x4 acc2[4] = {};
    const float* xb = x + (size_t)b * D1_IN * T_DIM;
    const float* Ab = A + (size_t)b * D1_IN * T_DIM;

    auto STAGE_XG = [&](int buf, int tc) {
        int t0 = tc * 64;
        int f = w * 4 + (l >> 4);                 // group w: rows 4w..4w+3
        gld16v(xb + (size_t)f * T_DIM + t0 + (l & 15) * 4, &xfst[buf][w * GSTR]);
        gld16v(Ab + (size_t)f * T_DIM + t0 + (l & 15) * 4, &gst[buf][w * GSTR]);
        if (w < 2) {
            int f2 = 32 + w * 4 + (l >> 4);       // groups 8,9: rows 32..39
            gld16v(xb + (size_t)f2 * T_DIM + t0 + (l & 15) * 4, &xfst[buf][(8 + w) * GSTR]);
            gld16v(Ab + (size_t)f2 * T_DIM + t0 + (l & 15) * 4, &gst[buf][(8 + w) * GSTR]);
        }
    };
    auto STAGE_W2 = [&](int tc) {
        gld16v(w2g + (size_t)tc * 4096 + w * 512 + l * 8, &w2s[w * 512]);
    };
    // CONVERT: one thread per (octet, t): 8 strided word reads (2-way broadcast,
    // free) -> one b128 write at octet-XOR-swizzled slot (b128 bank floor).
    auto CONVERT = [&](int buf) {
        if (tid < 320) {
            int oct = tid >> 6, tt = tid & 63;
            const float* base = &xfst[buf][0];
            float v[8];
            #pragma unroll
            for (int i = 0; i < 8; i++) {
                int f = oct * 8 + i;
                v[i] = base[(f >> 2) * GSTR + (f & 3) * 64 + tt];
            }
            uint4v pk;
            #pragma unroll
            for (int i = 0; i < 4; i++)
                pk[i] = (__float_as_uint(v[2 * i]) >> 16) | (__float_as_uint(v[2 * i + 1]) & 0xFFFF0000u);
            *(uint4v*)&xbt[tt * 72 + ((oct ^ ((tt >> 3) & 7)) << 3)] = pk;
        }
    };

    // zero ALL of xbt once: pad octets (swizzled slots never written) stay zero
    for (int i = tid; i < 2304; i += 512) ((unsigned int*)xbt)[i] = 0u;
    STAGE_XG(0, 0);
    __syncthreads();
    for (int tc = 0; tc < 16; tc++) {
        int cur = tc & 1;
        CONVERT(cur);
        STAGE_W2(tc);
        __syncthreads();                       // A: xbt + gst + w2s ready
        if (tc < 15) STAGE_XG(cur ^ 1, tc + 1);  // prefetch overlaps compute
        // X_bar^T via MFMA: frag read uses the same octet-XOR swizzle
        f32x4 acc1[4] = {};
        #pragma unroll
        for (int ni = 0; ni < 4; ni++) {
            int t = ni * 16 + rr;
            int sw = (t >> 3) & 7;
            #pragma unroll
            for (int ks = 0; ks < 2; ks++) {
                int oct = ks * 4 + q;
                bf16x8 bx = *(const bf16x8*)&xbt[t * 72 + ((oct ^ sw) << 3)];
                acc1[ni] = __builtin_amdgcn_mfma_f32_16x16x32_bf16(bx, aw[ks], acc1[ni], 0, 0, 0);
            }
        }
        // gate (fp32 LDS, lane-fixed row am) + pack -> one ds_write_b64 per ni
        const float* gr = &gst[cur][amg];
        #pragma unroll
        for (int ni = 0; ni < 4; ni++) {
            f32x4 gv = *(const f32x4*)(gr + ni * 16 + q * 4);
            float e0 = acc1[ni][0] * (lam * gv.x + oml);
            float e1 = acc1[ni][1] * (lam * gv.y + oml);
            float e2 = acc1[ni][2] * (lam * gv.z + oml);
            float e3 = acc1[ni][3] * (lam * gv.w + oml);
            uint2 pk;
            pk.x = (unsigned int)f2bf(e0) | ((unsigned int)f2bf(e1) << 16);
            pk.y = (unsigned int)f2bf(e2) | ((unsigned int)f2bf(e3) << 16);
            *(uint2*)&xtl[og * 72 + ni * 16 + q * 4] = pk;
        }
        // GEMM2: a2 row = og (same-wave RAW on xtl), b2 from swizzled w2s LDS
        #pragma unroll
        for (int ks2 = 0; ks2 < 2; ks2++) {
            bf16x8 a2 = *(const bf16x8*)&xtl[og * 72 + ks2 * 32 + q * 8];
            #pragma unroll
            for (int ni = 0; ni < 4; ni++) {
                int s = ni * 16 + rr;
                bf16x8 b2 = *(const bf16x8*)&w2s[s * 64 + (((ks2 * 4 + q) ^ (s & 7)) << 3)];
                acc2[ni] = __builtin_amdgcn_mfma_f32_16x16x32_bf16(a2, b2, acc2[ni], 0, 0, 0);
            }
        }
        __syncthreads();                       // B: drains prefetch; protects buffers
    }
    #pragma unroll
    for (int ni = 0; ni < 4; ni++)
        #pragma unroll
        for (int j = 0; j < 4; j++) {
            int row = w * 16 + q * 4 + j;
            if (row < D1_OUT) {
                int col = ni * 16 + rr;
                float v = acc2[ni][j] + Bias[row * D2_OUT + col];
                out[((size_t)b * D1_OUT + row) * D2_OUT + col] = fmaxf(v, 0.f);
            }
        }
}

extern "C" void kernel_launch(void* const* d_in, const int* in_sizes, int n_in,
                              void* d_out, int out_size, void* d_ws, size_t ws_size,
                              hipStream_t stream) {
    const float* x    = (const float*)d_in[0];
    const float* W1   = (const float*)d_in[1];
    const float* W    = (const float*)d_in[2];
    const float* W2   = (const float*)d_in[3];
    const float* Bias = (const float*)d_in[4];
    const float* lam  = (const float*)d_in[5];
    float* out = (float*)d_out;
    float* A   = out + OUT0_SZ;                    // second output region

    char* ws = (char*)d_ws;
    unsigned short* wfrag = (unsigned short*)(ws);              // 2 MB
    unsigned short* w2g   = (unsigned short*)(ws + 2097152);    // 128 KB
    unsigned short* w1p   = (unsigned short*)(ws + 2228224);    // 16 KB (total ~2.25 MB)

    hipLaunchKernelGGL(k_prep_small, dim3(73), dim3(256), 0, stream, W1, W, W2, w2g, w1p);
    hipLaunchKernelGGL(k_wfrag, dim3(256), dim3(256), 0, stream, W, wfrag);
    hipLaunchKernelGGL(k_mega, dim3(512), dim3(512), 0, stream, x, wfrag, w1p, w2g, Bias, lam, A, out);
}